// Round 1
// 647.177 us; speedup vs baseline: 1.0515x; 1.0515x over previous
//
#include <hip/hip_runtime.h>
#include <hip/hip_bf16.h>
#include <math.h>

#define NN   100000   // nodes
#define NNP  100096   // nodes padded to mult of 128 (GEMM staging reads, zero-filled)
#define DD   202      // feature dim
#define ET   6        // edge types
#define MM   200000   // edges per type
#define NE   (ET*MM)  // 1.2M edges
#define NPOS 512
#define GDP  204      // gating row stride (padded, zeros at 202..203)
#define DE   1212     // DD*ET
#define PDE  1216     // prop row stride (padded; 2432 B rows -> 16B-aligned, 64B-aligned)
#define KK   202      // GEMM K
#define KP   224      // K padded to 7*32
#define NP   1280     // N padded to 10*128

typedef __attribute__((ext_vector_type(8))) short bf16x8;
typedef __attribute__((ext_vector_type(4))) float f32x4;

static __device__ inline unsigned short f2b(float f) {
    union { __hip_bfloat16 h; unsigned short s; } u;
    u.h = __float2bfloat16(f);
    return u.s;
}

static __device__ inline void glds16(const unsigned short* g, unsigned short* l) {
    __builtin_amdgcn_global_load_lds(
        (const __attribute__((address_space(1))) unsigned int*)g,
        (__attribute__((address_space(3))) unsigned int*)l, 16, 0, 0);
}

// ---------------- pos_gating: (512 x GDP) = 2*sigmoid(pos_embs @ W_pos + b_pos), padded
__global__ void gating_kernel(const float* __restrict__ W_pos,
                              const float* __restrict__ b_pos,
                              float* __restrict__ gating) {
    int p = blockIdx.x;
    __shared__ float emb[DD];
    int t = threadIdx.x;
    if (t < 100) {
        float invf = expf(-((float)t / 100.0f) * 9.210340371976184f); // ln(10000)
        float si = (float)p * invf;
        emb[t]       = sinf(si);
        emb[100 + t] = cosf(si);
    } else if (t < 102) {
        emb[100 + t] = 0.0f;
    }
    __syncthreads();
    if (t < GDP) {
        float g = 0.0f;
        if (t < DD) {
            float acc = b_pos[t];
            for (int k = 0; k < DD; ++k) acc += emb[k] * W_pos[k * DD + t];
            g = 2.0f / (1.0f + expf(-acc));
        }
        gating[p * GDP + t] = g;   // zeros at 202,203
    }
}

// ---------------- W_transform (202x1212 fp32) -> Bt (1280x224 bf16, transposed, padded)
__global__ void convB_kernel(const float* __restrict__ W, unsigned short* __restrict__ Bt) {
    int id = blockIdx.x * 256 + threadIdx.x;
    if (id >= NP * KP) return;
    int n = id / KP, k = id % KP;
    float v = (k < KK && n < DE) ? W[(size_t)k * DE + n] : 0.0f;
    Bt[id] = f2b(v);
}

// ---------------- node_states (100000x202 fp32) -> Abf (100096x224 bf16, padded)
__global__ void convA_kernel(const float* __restrict__ A, unsigned short* __restrict__ Abf) {
    int id = blockIdx.x * 256 + threadIdx.x;         // one bf16 pair per thread
    if (id >= NNP * (KP / 2)) return;
    int row = id / (KP / 2), kp = (id % (KP / 2)) * 2;
    float2 v = make_float2(0.0f, 0.0f);
    if (row < NN && kp < KK) v = *(const float2*)&A[(size_t)row * KK + kp]; // kp<=200 -> ok
    ushort2 o; o.x = f2b(v.x); o.y = f2b(v.y);
    *(ushort2*)&Abf[(size_t)row * KP + kp] = o;
}

// ---------------- prop = Abf @ Bt^T + b -> bf16[NN][PDE], MFMA 128x128 tile
// global_load_lds staging (16B), XOR-swizzled LDS chunks, LDS-staged epilogue
__global__ __launch_bounds__(256) void gemm_mfma(const unsigned short* __restrict__ Abf,
                                                 const unsigned short* __restrict__ Bt,
                                                 const float* __restrict__ bias,
                                                 unsigned short* __restrict__ C) {
    __shared__ unsigned short sA[4096];   // 128 rows x 32 k (swizzled chunks)
    __shared__ unsigned short sB[4096];
    __shared__ unsigned short sE[4608];   // epilogue: 4 waves x 16 rows x 72 (stride-padded)
    int t    = threadIdx.x;
    int lane = t & 63;
    int wave = t >> 6;
    int q    = lane >> 4;
    int r16  = lane & 15;
    int wm   = (wave >> 1) * 64;
    int wn   = (wave & 1) * 64;
    int row0 = blockIdx.y * 128;
    int col0 = blockIdx.x * 128;

    // staging geometry: lane covers 16B; rows wave*32+i*16+lrow; chunk XOR-swizzled
    int lrow = lane >> 2;
    int gch  = (lane & 3) ^ ((lrow >> 1) & 3);     // global k-chunk this lane fetches
    const unsigned short* aS0 = Abf + (size_t)(row0 + wave * 32 + lrow) * KP + gch * 8;
    const unsigned short* aS1 = aS0 + 16 * KP;
    const unsigned short* bS0 = Bt  + (size_t)(col0 + wave * 32 + lrow) * KP + gch * 8;
    const unsigned short* bS1 = bS0 + 16 * KP;
    unsigned short* lA0 = &sA[(wave * 32) * 32];
    unsigned short* lA1 = &sA[(wave * 32 + 16) * 32];
    unsigned short* lB0 = &sB[(wave * 32) * 32];
    unsigned short* lB1 = &sB[(wave * 32 + 16) * 32];

    f32x4 acc[4][4] = {};
    int swzr = (r16 >> 1) & 3;

    for (int kc = 0; kc < KP; kc += 32) {
        glds16(aS0 + kc, lA0);
        glds16(aS1 + kc, lA1);
        glds16(bS0 + kc, lB0);
        glds16(bS1 + kc, lB1);
        __syncthreads();

        bf16x8 a[4], b[4];
        #pragma unroll
        for (int mi = 0; mi < 4; ++mi)
            a[mi] = *(const bf16x8*)&sA[(wm + mi * 16 + r16) * 32 + (q ^ swzr) * 8];
        #pragma unroll
        for (int ni = 0; ni < 4; ++ni)
            b[ni] = *(const bf16x8*)&sB[(wn + ni * 16 + r16) * 32 + (q ^ swzr) * 8];
        #pragma unroll
        for (int mi = 0; mi < 4; ++mi)
            #pragma unroll
            for (int ni = 0; ni < 4; ++ni)
                acc[mi][ni] = __builtin_amdgcn_mfma_f32_16x16x32_bf16(a[mi], b[ni], acc[mi][ni], 0, 0, 0);
        __syncthreads();
    }

    // epilogue: per-wave-private LDS staging -> 16B/lane aligned stores
    float bb[4];
    #pragma unroll
    for (int ni = 0; ni < 4; ++ni) {
        int col = col0 + wn + ni * 16 + r16;
        bb[ni] = (col < DE) ? bias[col] : 0.0f;
    }
    int epi = wave * 1152;            // 16 rows * 72
    int rl = lane >> 3, ck = lane & 7;
    #pragma unroll
    for (int mi = 0; mi < 4; ++mi) {
        #pragma unroll
        for (int ni = 0; ni < 4; ++ni)
            #pragma unroll
            for (int ri = 0; ri < 4; ++ri)
                sE[epi + (q * 4 + ri) * 72 + ni * 16 + r16] = f2b(acc[mi][ni][ri] + bb[ni]);
        #pragma unroll
        for (int ii = 0; ii < 2; ++ii) {
            int rr = ii * 8 + rl;
            bf16x8 v = *(const bf16x8*)&sE[epi + rr * 72 + ck * 8];
            int grow = row0 + wm + mi * 16 + rr;
            int gcol = col0 + wn + ck * 8;
            if (grow < NN && gcol < PDE)
                *(bf16x8*)&C[(size_t)grow * PDE + gcol] = v;
        }
    }
}

// ---------------- pass 1: histogram of targets
__global__ __launch_bounds__(256) void count_kernel(const int* __restrict__ edges,
                                                    int* __restrict__ count) {
    int i = blockIdx.x * 256 + threadIdx.x;
    if (i >= NE) return;
    atomicAdd(&count[edges[2 * i + 1]], 1);
}

// ---------------- pass 2: segment allocation (block scan + 1 atomic/block)
__global__ __launch_bounds__(256) void alloc_kernel(const int* __restrict__ count,
                                                    int* __restrict__ start,
                                                    int* __restrict__ cursor) {
    int t = blockIdx.x * 256 + threadIdx.x;
    int c = (t < NN) ? count[t] : 0;
    __shared__ int s[256];
    __shared__ int base;
    s[threadIdx.x] = c;
    __syncthreads();
    int v = c;
    for (int off = 1; off < 256; off <<= 1) {
        int u = (threadIdx.x >= off) ? s[threadIdx.x - off] : 0;
        __syncthreads();
        v += u;
        s[threadIdx.x] = v;
        __syncthreads();
    }
    if (threadIdx.x == 255) base = atomicAdd(cursor, v);
    __syncthreads();
    if (t < NN) start[t] = base + v - c;
}

// ---------------- pass 3: scatter PACKED edge records (start becomes segment END)
// record: src (17b) | e (3b) | pos (9b)  — removes the eidx->edges/pos_lists
// dependent-load chain from the gather kernel entirely.
__global__ __launch_bounds__(256) void scatter_kernel(const int* __restrict__ edges,
                                                      const int* __restrict__ pos_lists,
                                                      int* __restrict__ start,
                                                      unsigned* __restrict__ recs) {
    int i = blockIdx.x * 256 + threadIdx.x;
    if (i >= NE) return;
    int2 st = *(const int2*)&edges[2 * i];              // (src, tgt), 8B aligned
    int e = (int)((unsigned)i / MM);                    // edge type
    unsigned rec = (unsigned)st.x | ((unsigned)e << 17) | ((unsigned)pos_lists[i] << 20);
    int p = atomicAdd(&start[st.y], 1);
    recs[p] = rec;
}

// ---------------- pass 4: one wave per target; packed metadata; 4-wide edge groups
// Loads for 4 edges (8 independent global loads) issued back-to-back before any
// consumption -> 4x the memory-level parallelism of the 1-deep pipeline.
// Accumulation order over edges is unchanged (bit-identical numerics).
__global__ __launch_bounds__(256) void gather_kernel(const unsigned short* __restrict__ prop,
                                                     const float* __restrict__ gating,
                                                     const int* __restrict__ count,
                                                     const int* __restrict__ seg_end,
                                                     const unsigned* __restrict__ recs,
                                                     float* __restrict__ out) {
    int wid = blockIdx.x * 4 + (threadIdx.x >> 6);
    if (wid >= NN) return;
    int lane = threadIdx.x & 63;
    int c = count[wid];
    int end = seg_end[wid];
    int begin = end - c;
    int d = lane * 4;
    bool act = d < DD;                    // lanes 0..50
    float a0 = 0.f, a1 = 0.f, a2 = 0.f, a3 = 0.f;

    for (int base = begin; base < end; base += 64) {
        int n = end - base; if (n > 64) n = 64;
        unsigned rec = 0u;
        if (lane < n) rec = recs[base + lane];
        int poff = (int)(rec & 0x1FFFFu) * PDE + (int)((rec >> 17) & 7u) * DD;  // < 2^27
        int goff = (int)(rec >> 20) * GDP;

        for (int jj = 0; jj < n; jj += 4) {
            int j1 = (jj + 1 < n) ? jj + 1 : jj;   // clamped dup loads are L1-hits,
            int j2 = (jj + 2 < n) ? jj + 2 : jj;   // never consumed
            int j3 = (jj + 3 < n) ? jj + 3 : jj;
            int po0 = __shfl(poff, jj), go0 = __shfl(goff, jj);
            int po1 = __shfl(poff, j1), go1 = __shfl(goff, j1);
            int po2 = __shfl(poff, j2), go2 = __shfl(goff, j2);
            int po3 = __shfl(poff, j3), go3 = __shfl(goff, j3);
            uint2  pv0 = make_uint2(0u, 0u), pv1 = pv0, pv2 = pv0, pv3 = pv0;
            float4 gv0 = make_float4(0.f, 0.f, 0.f, 0.f), gv1 = gv0, gv2 = gv0, gv3 = gv0;
            if (act) {
                pv0 = *(const uint2*)&prop[po0 + d];
                pv1 = *(const uint2*)&prop[po1 + d];
                pv2 = *(const uint2*)&prop[po2 + d];
                pv3 = *(const uint2*)&prop[po3 + d];
                gv0 = *(const float4*)&gating[go0 + d];
                gv1 = *(const float4*)&gating[go1 + d];
                gv2 = *(const float4*)&gating[go2 + d];
                gv3 = *(const float4*)&gating[go3 + d];
            }
            a0 += __uint_as_float(pv0.x << 16)         * gv0.x;
            a1 += __uint_as_float(pv0.x & 0xffff0000u) * gv0.y;
            a2 += __uint_as_float(pv0.y << 16)         * gv0.z;
            a3 += __uint_as_float(pv0.y & 0xffff0000u) * gv0.w;
            if (jj + 1 < n) {               // n is wave-uniform: scalar branch, no divergence
                a0 += __uint_as_float(pv1.x << 16)         * gv1.x;
                a1 += __uint_as_float(pv1.x & 0xffff0000u) * gv1.y;
                a2 += __uint_as_float(pv1.y << 16)         * gv1.z;
                a3 += __uint_as_float(pv1.y & 0xffff0000u) * gv1.w;
            }
            if (jj + 2 < n) {
                a0 += __uint_as_float(pv2.x << 16)         * gv2.x;
                a1 += __uint_as_float(pv2.x & 0xffff0000u) * gv2.y;
                a2 += __uint_as_float(pv2.y << 16)         * gv2.z;
                a3 += __uint_as_float(pv2.y & 0xffff0000u) * gv2.w;
            }
            if (jj + 3 < n) {
                a0 += __uint_as_float(pv3.x << 16)         * gv3.x;
                a1 += __uint_as_float(pv3.x & 0xffff0000u) * gv3.y;
                a2 += __uint_as_float(pv3.y << 16)         * gv3.z;
                a3 += __uint_as_float(pv3.y & 0xffff0000u) * gv3.w;
            }
        }
    }

    float div = (c == 0 ? 1.0f : (float)c) + 1e-8f;
    float inv = 1.0f / div;
    if (act) {
        float* orow = out + (size_t)wid * DD;
        *(float2*)&orow[d] = make_float2(a0 * inv, a1 * inv);
        if (d + 2 < DD) *(float2*)&orow[d + 2] = make_float2(a2 * inv, a3 * inv);
    }
}

extern "C" void kernel_launch(void* const* d_in, const int* in_sizes, int n_in,
                              void* d_out, int out_size, void* d_ws, size_t ws_size,
                              hipStream_t stream) {
    const float* node_states = (const float*)d_in[0];
    const int*   edges       = (const int*)d_in[1];
    const int*   pos_lists   = (const int*)d_in[2];
    const float* W_transform = (const float*)d_in[3];
    const float* b_transform = (const float*)d_in[4];
    const float* W_pos       = (const float*)d_in[5];
    const float* b_pos       = (const float*)d_in[6];
    float* out = (float*)d_out;

    // workspace layout (16B-aligned blocks)
    float* gating   = (float*)d_ws;                               // 512*204*4    = 417,792 B
    int*   count    = (int*)(gating + NPOS * GDP);                // 400,000 B
    int*   start    = count + NN;                                 // 400,000 B
    int*   cursor   = start + NN;                                 // 16 B
    unsigned short* Bt  = (unsigned short*)(cursor + 4);          // 1280*224*2   = 573,440 B
    unsigned short* Abf = Bt + NP * KP;                           // 100096*224*2 = 44,843,008 B
    unsigned* recs  = (unsigned*)(Abf + (size_t)NNP * KP);        // 4,800,000 B
    unsigned short* prop = (unsigned short*)(recs + NE);          // 100000*1216*2 = 243,200,000 B

    hipMemsetAsync(count, 0, NN * sizeof(int), stream);
    hipMemsetAsync(cursor, 0, sizeof(int), stream);

    gating_kernel<<<NPOS, 256, 0, stream>>>(W_pos, b_pos, gating);
    convB_kernel<<<(NP * KP + 255) / 256, 256, 0, stream>>>(W_transform, Bt);
    convA_kernel<<<(NNP * (KP / 2) + 255) / 256, 256, 0, stream>>>(node_states, Abf);

    dim3 g2(NP / 128, NNP / 128);
    gemm_mfma<<<g2, 256, 0, stream>>>(Abf, Bt, b_transform, prop);

    count_kernel<<<(NE + 255) / 256, 256, 0, stream>>>(edges, count);
    alloc_kernel<<<(NN + 255) / 256, 256, 0, stream>>>(count, start, cursor);
    scatter_kernel<<<(NE + 255) / 256, 256, 0, stream>>>(edges, pos_lists, start, recs);
    gather_kernel<<<(NN + 3) / 4, 256, 0, stream>>>(prop, gating, count, start, recs, out);
}